// Round 4
// baseline (694.912 us; speedup 1.0000x reference)
//
#include <hip/hip_runtime.h>
#include <hip/hip_bf16.h>

#define N_ROWS 8192
#define DIM 512
#define C_CLSN 1000
#define LOW_THRE (1.0f / 1000.0f)
#define LDK 40   // padded LDS leading dim (bf16 elems) to break bank conflicts

typedef __bf16 bf16x8 __attribute__((ext_vector_type(8)));
typedef float floatx4 __attribute__((ext_vector_type(4)));

// ---------------- KZ: detect conf_mask storage (int32 / uint8 / int64) -------
__global__ __launch_bounds__(256) void kz_detect_v4(const int* __restrict__ conf,
                                                    int* __restrict__ flag) {
  __shared__ int sbad, sodd1, seven1;
  int tid = threadIdx.x;
  if (tid == 0) { sbad = 0; sodd1 = 0; seven1 = 0; }
  __syncthreads();
  for (int i = tid; i < 2048; i += 256) {   // 8 KB window: in-range for all layouts
    int v = conf[i];
    if (v != 0 && v != 1) atomicOr(&sbad, 1);
    if (v == 1) { if (i & 1) atomicAdd(&sodd1, 1); else atomicAdd(&seven1, 1); }
  }
  __syncthreads();
  if (tid == 0) {
    int mode = 0;                               // int32 0/1
    if (sbad) mode = 1;                         // packed uint8 bools
    else if (seven1 > 0 && sodd1 == 0) mode = 2; // int64 0/1 (odd words all 0)
    flag[0] = mode;
  }
}

// ---------------- KA: L2-normalize feature rows -> bf16 ----------------------
__global__ __launch_bounds__(64) void ka_featnorm_v4(const float* __restrict__ feature,
                                                     __bf16* __restrict__ featBF) {
  int r = blockIdx.x;
  int l = threadIdx.x;
  const float* fr = feature + (size_t)r * DIM;
  int c0 = l * 8;
  float4 v0 = *(const float4*)(fr + c0);
  float4 v1 = *(const float4*)(fr + c0 + 4);
  float ss = v0.x*v0.x + v0.y*v0.y + v0.z*v0.z + v0.w*v0.w
           + v1.x*v1.x + v1.y*v1.y + v1.z*v1.z + v1.w*v1.w;
  #pragma unroll
  for (int m = 1; m < 64; m <<= 1) ss += __shfl_xor(ss, m);
  float sc = 1.0f / fmaxf(sqrtf(ss), 1e-12f);
  bf16x8 bv;
  bv[0] = (__bf16)(v0.x * sc); bv[1] = (__bf16)(v0.y * sc);
  bv[2] = (__bf16)(v0.z * sc); bv[3] = (__bf16)(v0.w * sc);
  bv[4] = (__bf16)(v1.x * sc); bv[5] = (__bf16)(v1.y * sc);
  bv[6] = (__bf16)(v1.z * sc); bv[7] = (__bf16)(v1.w * sc);
  *(bf16x8*)(featBF + (size_t)r * DIM + c0) = bv;
}

// ---------------- KB: proj[c][d] = sum_k raw[c][k] * cP[d][k] ----------------
__global__ __launch_bounds__(256) void kb_proj_v4(const float* __restrict__ raw,
                                                  const float* __restrict__ cP,
                                                  float* __restrict__ proj) {
  int tid = threadIdx.x;
  int c0 = blockIdx.x * 8;
  __shared__ float sraw[8 * DIM];  // 16 KB
  for (int idx = tid; idx < 8 * DIM; idx += 256)
    sraw[idx] = raw[(size_t)c0 * DIM + idx];
  __syncthreads();
  int d0 = tid, d1 = tid + 256;
  float acc0[8], acc1[8];
  #pragma unroll
  for (int cc = 0; cc < 8; ++cc) { acc0[cc] = 0.f; acc1[cc] = 0.f; }
  for (int k = 0; k < DIM; k += 4) {
    float4 w0 = *(const float4*)&cP[(size_t)d0 * DIM + k];
    float4 w1 = *(const float4*)&cP[(size_t)d1 * DIM + k];
    #pragma unroll
    for (int cc = 0; cc < 8; ++cc) {
      const float* sr = &sraw[cc * DIM + k];
      acc0[cc] += sr[0]*w0.x + sr[1]*w0.y + sr[2]*w0.z + sr[3]*w0.w;
      acc1[cc] += sr[0]*w1.x + sr[1]*w1.y + sr[2]*w1.z + sr[3]*w1.w;
    }
  }
  #pragma unroll
  for (int cc = 0; cc < 8; ++cc) {
    proj[(size_t)(c0 + cc) * DIM + d0] = acc0[cc];
    proj[(size_t)(c0 + cc) * DIM + d1] = acc1[cc];
  }
}

// ---------------- KC: row-normalize proxy in place ---------------------------
__global__ __launch_bounds__(64) void kc_norm_v4(float* __restrict__ proxy) {
  int r = blockIdx.x, l = threadIdx.x;
  float* pr = proxy + (size_t)r * DIM;
  int c0 = l * 8;
  float4 v0 = *(float4*)(pr + c0);
  float4 v1 = *(float4*)(pr + c0 + 4);
  float ss = v0.x*v0.x + v0.y*v0.y + v0.z*v0.z + v0.w*v0.w
           + v1.x*v1.x + v1.y*v1.y + v1.z*v1.z + v1.w*v1.w;
  #pragma unroll
  for (int m = 1; m < 64; m <<= 1) ss += __shfl_xor(ss, m);
  float sc = 1.0f / fmaxf(sqrtf(ss), 1e-12f);
  v0.x *= sc; v0.y *= sc; v0.z *= sc; v0.w *= sc;
  v1.x *= sc; v1.y *= sc; v1.z *= sc; v1.w *= sc;
  *(float4*)(pr + c0)     = v0;
  *(float4*)(pr + c0 + 4) = v1;
}

// ---------------- KD: per-row prob processing --------------------------------
__global__ __launch_bounds__(256) void kd_prob_v4(const float* __restrict__ prob,
                                                  const int* __restrict__ conf,
                                                  const int* __restrict__ cmode,
                                                  const float* __restrict__ proxy,
                                                  const __bf16* __restrict__ featBF,
                                                  unsigned long long* __restrict__ bits,
                                                  float* __restrict__ pos,
                                                  int* __restrict__ counters) {
  int r = blockIdx.x;
  int tid = threadIdx.x;
  __shared__ unsigned long long sbits[16];
  __shared__ int scnt;
  __shared__ int scand[1024];
  __shared__ float swt[1024];
  __shared__ float redv[256];
  __shared__ int redi[256];
  int mode = cmode[0];
  bool is_conf;
  if (mode == 1)      is_conf = ((const unsigned char*)conf)[r] != 0;
  else if (mode == 2) is_conf = ((const long long*)conf)[r] != 0;
  else                is_conf = conf[r] != 0;
  if (tid < 16) sbits[tid] = 0ULL;
  if (tid == 0) scnt = 0;
  __syncthreads();
  const float* pr = prob + (size_t)r * C_CLSN;
  float bv = -1e30f; int bidx = 0x7fffffff;
  for (int c = tid; c < C_CLSN; c += 256) {
    float p = pr[c];
    if (p > bv) { bv = p; bidx = c; }  // ascending scan keeps first max per thread
    if (!is_conf && p > LOW_THRE) {
      int k = atomicAdd(&scnt, 1);
      scand[k] = c; swt[k] = p;
      atomicOr(&sbits[c >> 6], 1ULL << (c & 63));
    }
  }
  redv[tid] = bv; redi[tid] = bidx;
  __syncthreads();
  for (int s = 128; s > 0; s >>= 1) {
    if (tid < s) {
      float v2 = redv[tid + s]; int i2 = redi[tid + s];
      if (v2 > redv[tid] || (v2 == redv[tid] && i2 < redi[tid])) { redv[tid] = v2; redi[tid] = i2; }
    }
    __syncthreads();
  }
  int top1 = redi[0];
  if (tid == 0) {
    if (is_conf) {
      sbits[top1 >> 6] = 1ULL << (top1 & 63);  // one-hot pred_class
    } else {
      atomicAdd(&counters[0], scnt);  // sc_count
      atomicAdd(&counters[1], 1);     // denom
    }
  }
  __syncthreads();
  if (tid < 16) bits[(size_t)r * 16 + tid] = sbits[tid];
  // q_i and pos_pair
  float a0 = 0.f, a1 = 0.f;
  int d0 = tid, d1 = tid + 256;
  if (is_conf) {
    const float* pq = proxy + (size_t)top1 * DIM;
    a0 = pq[d0]; a1 = pq[d1];
  } else {
    int n = scnt;
    for (int e = 0; e < n; ++e) {
      int c = scand[e]; float w = swt[e];
      const float* pq = proxy + (size_t)c * DIM;
      a0 += w * pq[d0]; a1 += w * pq[d1];
    }
  }
  const __bf16* fr = featBF + (size_t)r * DIM;
  float dot = a0 * (float)fr[d0] + a1 * (float)fr[d1];
  __syncthreads();
  redv[tid] = dot;
  __syncthreads();
  for (int s = 128; s > 0; s >>= 1) {
    if (tid < s) redv[tid] += redv[tid + s];
    __syncthreads();
  }
  // |pos| <= 1 mathematically (unit rows, sum w <= 1); clamp is a safety no-op.
  if (tid == 0) pos[r] = fminf(fmaxf(redv[0], -1.1f), 1.1f);
}

// ---------------- KE: fused sim GEMM + bitset mask + masked sum(exp) ---------
__global__ __launch_bounds__(256) void ke_sim_v4(const __bf16* __restrict__ featBF,
                                                 const unsigned long long* __restrict__ bits,
                                                 float* __restrict__ S) {
  __shared__ __align__(16) __bf16 As[128 * LDK];            // 10240 B
  __shared__ __align__(16) __bf16 Bs[128 * LDK];            // 10240 B
  __shared__ unsigned long long bsI[16 * 128];              // 16384 B  [word][row]
  __shared__ unsigned long long bsJ[16 * 128];              // 16384 B  [word][col]

  int bi = blockIdx.x >> 6;
  int bj = blockIdx.x & 63;

  int tid = threadIdx.x;
  int wv = tid >> 6, lane = tid & 63;
  int wi = wv >> 1, wj = wv & 1;
  int lr = lane >> 4, lc = lane & 15;

  floatx4 acc[4][4];
  floatx4 zero = {0.f, 0.f, 0.f, 0.f};
  #pragma unroll
  for (int ti = 0; ti < 4; ++ti)
    #pragma unroll
    for (int tj = 0; tj < 4; ++tj) acc[ti][tj] = zero;

  const __bf16* Abase = featBF + (size_t)bi * 128 * DIM;
  const __bf16* Bbase = featBF + (size_t)bj * 128 * DIM;

  for (int kt = 0; kt < DIM; kt += 32) {
    __syncthreads();                    // protects previous iteration's frag reads
    #pragma unroll
    for (int t = 0; t < 2; ++t) {
      int idx = tid + t * 256;          // 0..511 : 128 rows x 4 chunks of 8 bf16
      int rw = idx >> 2, cc = (idx & 3) * 8;
      *(bf16x8*)&As[rw * LDK + cc] = *(const bf16x8*)&Abase[(size_t)rw * DIM + kt + cc];
      *(bf16x8*)&Bs[rw * LDK + cc] = *(const bf16x8*)&Bbase[(size_t)rw * DIM + kt + cc];
    }
    __syncthreads();
    // A/B frag: row = lane&15, k-chunk = lane>>4 (HW-verified, m89/m91)
    bf16x8 afr[4], bfr[4];
    #pragma unroll
    for (int ti = 0; ti < 4; ++ti)
      afr[ti] = *(bf16x8*)&As[(wi * 64 + ti * 16 + lc) * LDK + lr * 8];
    #pragma unroll
    for (int tj = 0; tj < 4; ++tj)
      bfr[tj] = *(bf16x8*)&Bs[(wj * 64 + tj * 16 + lc) * LDK + lr * 8];
    #pragma unroll
    for (int ti = 0; ti < 4; ++ti)
      #pragma unroll
      for (int tj = 0; tj < 4; ++tj)
        acc[ti][tj] = __builtin_amdgcn_mfma_f32_16x16x32_bf16(afr[ti], bfr[tj], acc[ti][tj], 0, 0, 0);
  }

  // stage bitsets transposed AFTER K-loop (dedicated LDS; barriers both sides)
  __syncthreads();
  #pragma unroll
  for (int e = 0; e < 8; ++e) {
    int flat = tid + e * 256;           // 0..2047
    int row = flat >> 4, w = flat & 15; // coalesced: 16 words/row contiguous
    bsI[w * 128 + row] = bits[(size_t)(bi * 128 + row) * 16 + w];
    bsJ[w * 128 + row] = bits[(size_t)(bj * 128 + row) * 16 + w];
  }
  __syncthreads();

  #pragma unroll
  for (int ti = 0; ti < 4; ++ti) {
    int ibase = wi * 64 + ti * 16 + lr * 4;   // C/D: row=(lane>>4)*4+reg, col=lane&15
    unsigned inter[16];
    #pragma unroll
    for (int q = 0; q < 16; ++q) inter[q] = 0u;
    #pragma unroll
    for (int w = 0; w < 16; ++w) {
      unsigned long long aw[4], bw[4];
      #pragma unroll
      for (int rr = 0; rr < 4; ++rr) aw[rr] = bsI[w * 128 + ibase + rr];
      #pragma unroll
      for (int tj = 0; tj < 4; ++tj) bw[tj] = bsJ[w * 128 + wj * 64 + tj * 16 + lc];
      #pragma unroll
      for (int rr = 0; rr < 4; ++rr)
        #pragma unroll
        for (int tj = 0; tj < 4; ++tj) {
          unsigned long long t = aw[rr] & bw[tj];
          inter[rr * 4 + tj] |= (unsigned)(t | (t >> 32));
        }
    }
    float rs[4] = {0.f, 0.f, 0.f, 0.f};
    #pragma unroll
    for (int rr = 0; rr < 4; ++rr)
      #pragma unroll
      for (int tj = 0; tj < 4; ++tj) {
        float sim = acc[ti][tj][rr];
        sim = fminf(sim, 1.0f);   // no-op for unit rows; bounds any residual bug
        float e_ = ((inter[rr * 4 + tj] == 0u) && (sim >= 1e-6f)) ? __expf(sim) : 0.f;
        rs[rr] += e_;
      }
    #pragma unroll
    for (int m = 1; m < 16; m <<= 1)
      #pragma unroll
      for (int rr = 0; rr < 4; ++rr) rs[rr] += __shfl_xor(rs[rr], m);
    if (lc == 0) {
      #pragma unroll
      for (int rr = 0; rr < 4; ++rr)
        atomicAdd(&S[(size_t)bi * 128 + ibase + rr], rs[rr]);
    }
  }
}

// ---------------- KF: final reduction — FP32 OUTPUT --------------------------
__global__ __launch_bounds__(256) void kf_final_v4(const float* __restrict__ pos,
                                                   const float* __restrict__ S,
                                                   const int* __restrict__ counters,
                                                   float* __restrict__ out) {
  __shared__ float red[256];
  int tid = threadIdx.x;
  float local = 0.f;
  for (int i = tid; i < N_ROWS; i += 256) {
    float p = pos[i];
    float s = fmaxf(S[i], 0.0f);
    local += logf(expf(p) + s) - p;   // -logp[:,0]
  }
  red[tid] = local;
  __syncthreads();
  for (int s = 128; s > 0; s >>= 1) {
    if (tid < s) red[tid] += red[tid + s];
    __syncthreads();
  }
  if (tid == 0) {
    float loss = red[0] / (float)N_ROWS;
    int scc = counters[0], dn = counters[1];
    float scn = (dn > 0) ? ((float)scc / (float)(dn > 1 ? dn : 1)) : 0.f;
    out[0] = loss;     // reference output dtype is float32 (two f32 scalars)
    out[1] = scn;
  }
}

extern "C" void kernel_launch(void* const* d_in, const int* in_sizes, int n_in,
                              void* d_out, int out_size, void* d_ws, size_t ws_size,
                              hipStream_t stream) {
  const float* feature   = (const float*)d_in[0];
  const float* proxy_raw = (const float*)d_in[1];
  const float* cP        = (const float*)d_in[2];
  const float* prob      = (const float*)d_in[3];
  const int*   conf      = (const int*)d_in[4];
  float* out = (float*)d_out;

  size_t need = (size_t)N_ROWS * DIM * 2      // featBF   8 MB
              + (size_t)C_CLSN * DIM * 4      // proxy    2 MB
              + (size_t)N_ROWS * 16 * 8       // bits     1 MB
              + (size_t)N_ROWS * 4            // pos
              + (size_t)N_ROWS * 4            // S
              + 256;                          // counters + cmode flag
  if (ws_size < need) return;                 // out stays 0 -> err 8.0625 signature

  char* ws = (char*)d_ws;
  __bf16* featBF = (__bf16*)ws;                       ws += (size_t)N_ROWS * DIM * 2;
  float* proxy = (float*)ws;                          ws += (size_t)C_CLSN * DIM * 4;
  unsigned long long* bits = (unsigned long long*)ws; ws += (size_t)N_ROWS * 16 * 8;
  float* pos = (float*)ws;                            ws += (size_t)N_ROWS * 4;
  float* S = (float*)ws;                              ws += (size_t)N_ROWS * 4;
  int* counters = (int*)ws;                           // [0]=sc_count [1]=denom [2]=cmode

  hipMemsetAsync(S, 0, (size_t)N_ROWS * 4 + 256, stream);  // S + counters contiguous
  kz_detect_v4<<<1, 256, 0, stream>>>(conf, &counters[2]);
  ka_featnorm_v4<<<N_ROWS, 64, 0, stream>>>(feature, featBF);
  kb_proj_v4<<<C_CLSN / 8, 256, 0, stream>>>(proxy_raw, cP, proxy);
  kc_norm_v4<<<C_CLSN, 64, 0, stream>>>(proxy);
  kd_prob_v4<<<N_ROWS, 256, 0, stream>>>(prob, conf, &counters[2], proxy, featBF, bits, pos, counters);
  ke_sim_v4<<<64 * 64, 256, 0, stream>>>(featBF, bits, S);
  kf_final_v4<<<1, 256, 0, stream>>>(pos, S, counters, out);
}